// Round 11
// baseline (27.855 us; speedup 1.0000x reference)
//
#include <hip/hip_runtime.h>
#include <hip/hip_fp16.h>
#include <math.h>

constexpr int B = 64, L = 2048, D = 1024, P = 512, C = 32;
constexpr int CH1 = 64;                 // stage-1 K chunk
constexpr int NK  = 3072 / CH1;         // 48 k-chunks
constexpr int GRID = 4 * NK;            // 192 blocks
constexpr int NT  = 512;
constexpr unsigned MAGIC = 0x5F3C9E71u; // != 0xAA poison, != 0

// ws layout in float units (all 8B-aligned offsets)
constexpr size_t P1_FLOATS = (size_t)NK * B * P;     // 1,572,864
constexpr size_t OFF_FLAGS = P1_FLOATS;              // 256 floats (192 used)
constexpr size_t OFF_WHIDH = OFF_FLAGS + 256;        // 512*512 halfs = 131072 floats
constexpr size_t OFF_WSCT  = OFF_WHIDH + 131072;     // 32*512 halfs (transposed)

__device__ __forceinline__ void st8_agent(void* p, unsigned long long v) {
    __hip_atomic_store((unsigned long long*)p, v, __ATOMIC_RELAXED,
                       __HIP_MEMORY_SCOPE_AGENT);    // sc0+sc1: straight to L3
}

// Single kernel. All cross-block data written with agent-scope relaxed 8B
// atomic stores (bypass L1/L2 -> L3 coherence point), so the producer release
// fence has a CLEAN L2 (no writeback cost) and the consumer acquire fence is a
// pure invalidate. Poll is relaxed (no per-iteration invalidate).
__global__ __launch_bounds__(NT) void relpred_mono(
    const float* __restrict__ enc, const int* __restrict__ prep_idx,
    const float* __restrict__ Wh, const float* __restrict__ Wp,
    const float* __restrict__ Wc, const float* __restrict__ Whid,
    const float* __restrict__ Wsc, float* __restrict__ out,
    float* __restrict__ ws)
{
    float*    partial1 = ws;
    unsigned* flags    = (unsigned*)(ws + OFF_FLAGS);
    __half*   whid_h   = (__half*)(ws + OFF_WHIDH);
    __half*   wsc_t    = (__half*)(ws + OFF_WSCT);

    const int tid = threadIdx.x;
    const int bx  = blockIdx.x;

    __shared__ __align__(16) float smem[64 * 68 + 64 * 128];   // 50 KB, aliased

    // ================= producer =================
    {
        float* Xt = smem;             // [64][68] transposed X chunk (+pad)
        float* Wl = smem + 64 * 68;   // [64][128]
        const int ct   = bx & 3;
        const int kc   = bx >> 2;
        const int m    = kc >> 4;                 // 0=head,1=prep,2=child
        const int koff = (kc & 15) * CH1;
        const float* Wm = (m == 0) ? Wh : (m == 1) ? Wp : Wc;

        #pragma unroll
        for (int i = tid; i < 64 * 32; i += NT) {          // W tile 64x128
            const int r = i >> 5, c4 = (i & 31) * 4;
            *(float4*)&Wl[r * 128 + c4] =
                *(const float4*)&Wm[(size_t)(koff + r) * P + ct * 128 + c4];
        }
        #pragma unroll
        for (int i = tid; i < 64 * 16; i += NT) {          // X gather, transposed
            const int b = i >> 4, q = i & 15;
            const int row = prep_idx[b] + m - 1;
            const float4 v = *(const float4*)&enc[((size_t)b * L + row) * D + koff + q * 4];
            Xt[(q * 4 + 0) * 68 + b] = v.x;
            Xt[(q * 4 + 1) * 68 + b] = v.y;
            Xt[(q * 4 + 2) * 68 + b] = v.z;
            Xt[(q * 4 + 3) * 68 + b] = v.w;
        }

        // conversion side job: whid 32768 tasks of 8 halfs; wsc_t 4096 tasks of 4
        {
            const int gid = bx * NT + tid;                 // 0..98303
            if (gid < 32768) {
                const int p = gid >> 6, q8 = (gid & 63) * 8;
                const float4 v0 = *(const float4*)&Whid[(size_t)p * P + q8];
                const float4 v1 = *(const float4*)&Whid[(size_t)p * P + q8 + 4];
                union { unsigned long long u; __half2 h[2]; } pk;
                pk.h[0] = __floats2half2_rn(v0.x, v0.y);
                pk.h[1] = __floats2half2_rn(v0.z, v0.w);
                st8_agent(&whid_h[(size_t)p * P + q8], pk.u);
                pk.h[0] = __floats2half2_rn(v1.x, v1.y);
                pk.h[1] = __floats2half2_rn(v1.z, v1.w);
                st8_agent(&whid_h[(size_t)p * P + q8 + 4], pk.u);
            } else if (gid < 32768 + 4096) {
                const int j = gid - 32768;                 // c = j&31, p0 = (j>>5)*4
                const int c = j & 31, p0 = (j >> 5) * 4;
                union { unsigned long long u; __half h[4]; } pk;
                #pragma unroll
                for (int i = 0; i < 4; ++i)
                    pk.h[i] = __float2half(Wsc[(size_t)(p0 + i) * C + c]);
                st8_agent(&wsc_t[(size_t)c * P + p0], pk.u);
            }
        }
        __syncthreads();

        const int ty = tid >> 5, tx = tid & 31;   // 16 batch-groups x 32 col-groups
        float acc[4][4];
        #pragma unroll
        for (int i = 0; i < 4; ++i)
            #pragma unroll
            for (int j = 0; j < 4; ++j) acc[i][j] = 0.f;

        #pragma unroll 8
        for (int k = 0; k < CH1; ++k) {
            const float4 xv = *(float4*)&Xt[k * 68 + ty * 4];
            const float4 wv = *(float4*)&Wl[k * 128 + tx * 4];
            const float xs[4] = {xv.x, xv.y, xv.z, xv.w};
            const float wf[4] = {wv.x, wv.y, wv.z, wv.w};
            #pragma unroll
            for (int i = 0; i < 4; ++i)
                #pragma unroll
                for (int j = 0; j < 4; ++j) acc[i][j] += xs[i] * wf[j];
        }
        #pragma unroll
        for (int i = 0; i < 4; ++i) {
            const int b = ty * 4 + i;
            union { unsigned long long u[2]; float f[4]; } pk;
            pk.f[0] = acc[i][0]; pk.f[1] = acc[i][1];
            pk.f[2] = acc[i][2]; pk.f[3] = acc[i][3];
            float* dst = &partial1[((size_t)kc * B + b) * P + ct * 128 + tx * 4];
            st8_agent(dst,     pk.u[0]);
            st8_agent(dst + 2, pk.u[1]);
        }
    }
    __syncthreads();                   // vmcnt(0): all sc1 stores at L3
    if (tid == 0) {
        __builtin_amdgcn_fence(__ATOMIC_RELEASE, "agent");   // L2 clean -> cheap
        __hip_atomic_store(&flags[bx], MAGIC, __ATOMIC_RELAXED, __HIP_MEMORY_SCOPE_AGENT);
    }
    if (bx >= B) return;               // blocks 64..191 retire

    // ================= consumer: batch b = bx =================
    const int b = bx;
    if (tid < GRID) {                  // relaxed poll (L3-direct), one flag/thread
        const unsigned* f = &flags[tid];
        int spins = 0;
        while (__hip_atomic_load(f, __ATOMIC_RELAXED, __HIP_MEMORY_SCOPE_AGENT) != MAGIC) {
            __builtin_amdgcn_s_sleep(2);
            if (++spins > 200000) {    // bounded fallback (R7-proven progress)
                while (__hip_atomic_load(f, __ATOMIC_ACQUIRE, __HIP_MEMORY_SCOPE_AGENT) != MAGIC)
                    __builtin_amdgcn_s_sleep(2);
                break;
            }
        }
    }
    __syncthreads();
    __builtin_amdgcn_fence(__ATOMIC_ACQUIRE, "agent");       // one invalidate

    float* c1s  = smem;                         // [512]
    float* pbuf = smem + 512;                   // [8][512]
    float* c2s  = smem + 512 + 4096;            // [512]
    float* sp   = smem + 512 + 4096 + 512;      // [16][32]

    // ---- A: reduce 48 split-K partials + tanh -> c1 ----
    {
        const int g = tid >> 7, qq = tid & 127;   // 4 groups x 12 chunks
        float4 a = make_float4(0.f, 0.f, 0.f, 0.f);
        #pragma unroll 4
        for (int kc = g * 12; kc < g * 12 + 12; ++kc) {
            const float4 v = *(const float4*)&partial1[((size_t)kc * B + b) * P + qq * 4];
            a.x += v.x; a.y += v.y; a.z += v.z; a.w += v.w;
        }
        *(float4*)&pbuf[(g * 128 + qq) * 4] = a;
    }
    __syncthreads();
    {
        const float s = pbuf[tid] + pbuf[512 + tid] + pbuf[1024 + tid] + pbuf[1536 + tid];
        c1s[tid] = tanhf(s);
    }
    __syncthreads();

    // ---- B: c2 = tanh(c1 @ Whid_fp16); 8 p-groups x 64 q-octets, uint4 loads ----
    {
        const int qo = tid & 63, pg = tid >> 6;
        float a[8];
        #pragma unroll
        for (int j = 0; j < 8; ++j) a[j] = 0.f;
        #pragma unroll 4
        for (int k = 0; k < 64; ++k) {
            const int p = pg * 64 + k;
            const float cv = c1s[p];             // wave-broadcast
            union { uint4 u; __half2 h[4]; } w;
            w.u = *(const uint4*)&whid_h[(size_t)p * P + qo * 8];
            float2 f;
            f = __half22float2(w.h[0]); a[0] += cv * f.x; a[1] += cv * f.y;
            f = __half22float2(w.h[1]); a[2] += cv * f.x; a[3] += cv * f.y;
            f = __half22float2(w.h[2]); a[4] += cv * f.x; a[5] += cv * f.y;
            f = __half22float2(w.h[3]); a[6] += cv * f.x; a[7] += cv * f.y;
        }
        #pragma unroll
        for (int j = 0; j < 8; ++j) pbuf[pg * 512 + qo * 8 + j] = a[j];
    }
    __syncthreads();
    {
        float s = 0.f;
        #pragma unroll
        for (int g = 0; g < 8; ++g) s += pbuf[g * 512 + tid];
        c2s[tid] = tanhf(s);
    }
    __syncthreads();

    // ---- C: scorer via transposed fp16 Wsc + softmax ----
    {
        const int c = tid & 31, g = tid >> 5;    // 16 groups x 32 p's
        float s = 0.f;
        #pragma unroll
        for (int t = 0; t < 4; ++t) {
            const int p0 = g * 32 + t * 8;
            union { uint4 u; __half2 h[4]; } w;
            w.u = *(const uint4*)&wsc_t[(size_t)c * P + p0];
            float2 f;
            f = __half22float2(w.h[0]); s += c2s[p0+0]*f.x + c2s[p0+1]*f.y;
            f = __half22float2(w.h[1]); s += c2s[p0+2]*f.x + c2s[p0+3]*f.y;
            f = __half22float2(w.h[2]); s += c2s[p0+4]*f.x + c2s[p0+5]*f.y;
            f = __half22float2(w.h[3]); s += c2s[p0+6]*f.x + c2s[p0+7]*f.y;
        }
        sp[g * C + c] = s;
    }
    __syncthreads();
    if (tid < C) {
        float sc = 0.f;
        #pragma unroll
        for (int g = 0; g < 16; ++g) sc += sp[g * C + tid];
        float m = sc;
        #pragma unroll
        for (int off = 16; off; off >>= 1) m = fmaxf(m, __shfl_xor(m, off));
        const float e = expf(sc - m);
        float ssum = e;
        #pragma unroll
        for (int off = 16; off; off >>= 1) ssum += __shfl_xor(ssum, off);
        out[b * C + tid] = e / ssum;
    }
}

extern "C" void kernel_launch(void* const* d_in, const int* in_sizes, int n_in,
                              void* d_out, int out_size, void* d_ws, size_t ws_size,
                              hipStream_t stream) {
    const float* enc      = (const float*)d_in[0];
    const int*   prep_idx = (const int*)  d_in[1];
    const float* Wh       = (const float*)d_in[2];
    const float* Wp       = (const float*)d_in[3];
    const float* Wc       = (const float*)d_in[4];
    const float* Whid     = (const float*)d_in[5];
    const float* Wsc      = (const float*)d_in[6];
    float*       out      = (float*)d_out;
    float*       wsf      = (float*)d_ws;

    (void)in_sizes; (void)n_in; (void)out_size; (void)ws_size;

    relpred_mono<<<GRID, NT, 0, stream>>>(enc, prep_idx, Wh, Wp, Wc,
                                          Whid, Wsc, out, wsf);
}

// Round 12
// 23.852 us; speedup vs baseline: 1.1678x; 1.1678x over previous
//
#include <hip/hip_runtime.h>
#include <hip/hip_fp16.h>
#include <math.h>

constexpr int B = 64, L = 2048, D = 1024, P = 512, C = 32;
constexpr int CH1 = 64;                 // stage-1 K chunk
constexpr int NK  = 3072 / CH1;         // 48 k-chunks
constexpr int G1  = 4 * NK;             // 192 blocks

// ws layout in BYTES
constexpr size_t P1_HALFS   = (size_t)NK * B * P;          // 1,572,864 halfs
constexpr size_t OFF_WHIDH  = P1_HALFS * 2;                // 3,145,728
constexpr size_t OFF_WSCT   = OFF_WHIDH + (size_t)P * P * 2;   // +524,288

// ===================== K1: split-K stage-1 GEMM (fp16 partials) ================
// partial1h[kc][b][p] = fp16( X[b, k-chunk] dot W1[k-chunk, p] )
// Side jobs: Whid -> fp16 row-major; Wsc -> fp16 transposed wsc_t[c][p].
__global__ __launch_bounds__(256) void k1_stage1(
    const float* __restrict__ enc, const int* __restrict__ prep_idx,
    const float* __restrict__ Wh, const float* __restrict__ Wp,
    const float* __restrict__ Wc, const float* __restrict__ Whid,
    const float* __restrict__ Wsc, __half* __restrict__ partial1h,
    __half* __restrict__ whid_h, __half* __restrict__ wsc_t)
{
    const int tid = threadIdx.x;
    const int ct  = blockIdx.x & 3;            // col tile (128 cols)
    const int kc  = blockIdx.x >> 2;           // k-chunk 0..47
    const int m    = kc >> 4;                  // 0=head,1=prep,2=child
    const int koff = (kc & 15) * CH1;
    const float* Wm = (m == 0) ? Wh : (m == 1) ? Wp : Wc;

    __shared__ float Xt[CH1][68];              // transposed X chunk (+pad)
    __shared__ float Wl[CH1][128];

    // conversion side job: Whid 65536 float4-quads; Wsc 16384 scalars transposed
    for (int gid = blockIdx.x * 256 + tid; gid < 65536 + 16384; gid += G1 * 256) {
        if (gid < 65536) {
            const float4 v = *(const float4*)&Whid[(size_t)gid * 4];
            *(__half2*)&whid_h[(size_t)gid * 4]     = __floats2half2_rn(v.x, v.y);
            *(__half2*)&whid_h[(size_t)gid * 4 + 2] = __floats2half2_rn(v.z, v.w);
        } else {
            const int j = gid - 65536;         // j = p*32 + c
            const int p = j >> 5, c = j & 31;
            wsc_t[(size_t)c * P + p] = __float2half(Wsc[j]);
        }
    }

    // stage W chunk: 64 x 128, coalesced float4
    for (int i = tid; i < CH1 * 32; i += 256) {
        const int r = i >> 5, c4 = (i & 31) * 4;
        *(float4*)&Wl[r][c4] =
            *(const float4*)&Wm[(size_t)(koff + r) * P + ct * 128 + c4];
    }
    // stage X chunk (gather row prep+m-1 per batch), transposed
    for (int i = tid; i < 64 * 16; i += 256) {
        const int b = i >> 4, q = i & 15;
        const int row = prep_idx[b] + m - 1;
        const float4 v = *(const float4*)&enc[((size_t)b * L + row) * D + koff + q * 4];
        Xt[q*4+0][b] = v.x; Xt[q*4+1][b] = v.y;
        Xt[q*4+2][b] = v.z; Xt[q*4+3][b] = v.w;
    }
    __syncthreads();

    const int ty = tid >> 4, tx = tid & 15;    // 16 batch-groups x 16 col-groups
    float acc[4][8];
    #pragma unroll
    for (int i = 0; i < 4; ++i)
        #pragma unroll
        for (int j = 0; j < 8; ++j) acc[i][j] = 0.f;

    #pragma unroll 4
    for (int k = 0; k < CH1; ++k) {
        const float4 xv = *(float4*)&Xt[k][ty * 4];
        const float4 w0 = *(float4*)&Wl[k][tx * 8];
        const float4 w1 = *(float4*)&Wl[k][tx * 8 + 4];
        const float xs[4]  = {xv.x, xv.y, xv.z, xv.w};
        const float ws8[8] = {w0.x, w0.y, w0.z, w0.w, w1.x, w1.y, w1.z, w1.w};
        #pragma unroll
        for (int i = 0; i < 4; ++i)
            #pragma unroll
            for (int j = 0; j < 8; ++j) acc[i][j] += xs[i] * ws8[j];
    }

    #pragma unroll
    for (int i = 0; i < 4; ++i) {
        const int b = ty * 4 + i;
        union { uint4 u; __half2 h[4]; } pk;
        #pragma unroll
        for (int j = 0; j < 4; ++j)
            pk.h[j] = __floats2half2_rn(acc[i][2*j], acc[i][2*j+1]);
        *(uint4*)&partial1h[((size_t)kc * B + b) * P + ct * 128 + tx * 8] = pk.u;
    }
}

// ===================== K2: per-batch tail (all-fp16 streams, prefetch) ==========
__global__ __launch_bounds__(512) void k2_tail(
    const __half* __restrict__ partial1h, const __half* __restrict__ whid_h,
    const __half* __restrict__ wsc_t, float* __restrict__ out)
{
    const int b   = blockIdx.x;
    const int tid = threadIdx.x;

    __shared__ __align__(16) float smem[512 + 4096 + 512 + 16 * 32];
    float* c1s  = smem;                         // [512]
    float* pbuf = smem + 512;                   // [8][512]
    float* c2s  = smem + 512 + 4096;            // [512]
    float* sp   = smem + 512 + 4096 + 512;      // [16][32]

    const int qo = tid & 63, pg = tid >> 6;     // phase-B coords (also used below)

    // ---- prefetch first 8 phase-B weight rows (independent of phase A) ----
    uint4 pre[8];
    #pragma unroll
    for (int k = 0; k < 8; ++k)
        pre[k] = *(const uint4*)&whid_h[(size_t)(pg * 64 + k) * P + qo * 8];

    // ---- A: reduce 48 fp16 split-K partials + tanh -> c1 ----
    {
        const int g = tid >> 6, p8 = (tid & 63) * 8;   // 8 groups x 6 chunks
        float a[8];
        #pragma unroll
        for (int j = 0; j < 8; ++j) a[j] = 0.f;
        #pragma unroll
        for (int kc = g * 6; kc < g * 6 + 6; ++kc) {
            union { uint4 u; __half2 h[4]; } w;
            w.u = *(const uint4*)&partial1h[((size_t)kc * B + b) * P + p8];
            float2 f;
            f = __half22float2(w.h[0]); a[0] += f.x; a[1] += f.y;
            f = __half22float2(w.h[1]); a[2] += f.x; a[3] += f.y;
            f = __half22float2(w.h[2]); a[4] += f.x; a[5] += f.y;
            f = __half22float2(w.h[3]); a[6] += f.x; a[7] += f.y;
        }
        #pragma unroll
        for (int j = 0; j < 8; ++j) pbuf[(tid >> 6) * 512 + p8 + j] = a[j];
    }
    __syncthreads();
    {
        float s = 0.f;
        #pragma unroll
        for (int g = 0; g < 8; ++g) s += pbuf[g * 512 + tid];
        c1s[tid] = tanhf(s);
    }
    __syncthreads();

    // ---- B: c2 = tanh(c1 @ Whid_fp16); 8 p-groups x 64 q-octets ----
    {
        float a[8];
        #pragma unroll
        for (int j = 0; j < 8; ++j) a[j] = 0.f;
        #pragma unroll
        for (int k = 0; k < 8; ++k) {           // prefetched rows
            const float cv = c1s[pg * 64 + k];
            union { uint4 u; __half2 h[4]; } w; w.u = pre[k];
            float2 f;
            f = __half22float2(w.h[0]); a[0] += cv * f.x; a[1] += cv * f.y;
            f = __half22float2(w.h[1]); a[2] += cv * f.x; a[3] += cv * f.y;
            f = __half22float2(w.h[2]); a[4] += cv * f.x; a[5] += cv * f.y;
            f = __half22float2(w.h[3]); a[6] += cv * f.x; a[7] += cv * f.y;
        }
        #pragma unroll 4
        for (int k = 8; k < 64; ++k) {
            const int p = pg * 64 + k;
            const float cv = c1s[p];
            union { uint4 u; __half2 h[4]; } w;
            w.u = *(const uint4*)&whid_h[(size_t)p * P + qo * 8];
            float2 f;
            f = __half22float2(w.h[0]); a[0] += cv * f.x; a[1] += cv * f.y;
            f = __half22float2(w.h[1]); a[2] += cv * f.x; a[3] += cv * f.y;
            f = __half22float2(w.h[2]); a[4] += cv * f.x; a[5] += cv * f.y;
            f = __half22float2(w.h[3]); a[6] += cv * f.x; a[7] += cv * f.y;
        }
        #pragma unroll
        for (int j = 0; j < 8; ++j) pbuf[pg * 512 + qo * 8 + j] = a[j];
    }
    __syncthreads();
    {
        float s = 0.f;
        #pragma unroll
        for (int g = 0; g < 8; ++g) s += pbuf[g * 512 + tid];
        c2s[tid] = tanhf(s);
    }
    __syncthreads();

    // ---- C: scorer via transposed fp16 Wsc + softmax ----
    {
        const int c = tid & 31, g = tid >> 5;    // 16 groups x 32 p's
        float s = 0.f;
        #pragma unroll
        for (int t = 0; t < 4; ++t) {
            const int p0 = g * 32 + t * 8;
            union { uint4 u; __half2 h[4]; } w;
            w.u = *(const uint4*)&wsc_t[(size_t)c * P + p0];
            float2 f;
            f = __half22float2(w.h[0]); s += c2s[p0+0]*f.x + c2s[p0+1]*f.y;
            f = __half22float2(w.h[1]); s += c2s[p0+2]*f.x + c2s[p0+3]*f.y;
            f = __half22float2(w.h[2]); s += c2s[p0+4]*f.x + c2s[p0+5]*f.y;
            f = __half22float2(w.h[3]); s += c2s[p0+6]*f.x + c2s[p0+7]*f.y;
        }
        sp[g * C + c] = s;
    }
    __syncthreads();
    if (tid < C) {
        float sc = 0.f;
        #pragma unroll
        for (int g = 0; g < 16; ++g) sc += sp[g * C + tid];
        float m = sc;
        #pragma unroll
        for (int off = 16; off; off >>= 1) m = fmaxf(m, __shfl_xor(m, off));
        const float e = expf(sc - m);
        float ssum = e;
        #pragma unroll
        for (int off = 16; off; off >>= 1) ssum += __shfl_xor(ssum, off);
        out[b * C + tid] = e / ssum;
    }
}

extern "C" void kernel_launch(void* const* d_in, const int* in_sizes, int n_in,
                              void* d_out, int out_size, void* d_ws, size_t ws_size,
                              hipStream_t stream) {
    const float* enc      = (const float*)d_in[0];
    const int*   prep_idx = (const int*)  d_in[1];
    const float* Wh       = (const float*)d_in[2];
    const float* Wp       = (const float*)d_in[3];
    const float* Wc       = (const float*)d_in[4];
    const float* Whid     = (const float*)d_in[5];
    const float* Wsc      = (const float*)d_in[6];
    float*       out      = (float*)d_out;

    __half* partial1h = (__half*)d_ws;
    __half* whid_h    = (__half*)((char*)d_ws + OFF_WHIDH);
    __half* wsc_t     = (__half*)((char*)d_ws + OFF_WSCT);

    (void)in_sizes; (void)n_in; (void)out_size; (void)ws_size;

    k1_stage1<<<G1, 256, 0, stream>>>(enc, prep_idx, Wh, Wp, Wc, Whid, Wsc,
                                      partial1h, whid_h, wsc_t);
    k2_tail<<<B, 512, 0, stream>>>(partial1h, whid_h, wsc_t, out);
}